// Round 11
// baseline (182.032 us; speedup 1.0000x reference)
//
#include <hip/hip_runtime.h>
#include <math.h>

#define NPTS 2048
#define BATCH 16
#define KNN 16
#define HID 128
#define RPB 8          // rows (queries) per block = waves per block
#define CAP 128        // compacted-candidate capacity per wave

typedef __attribute__((ext_vector_type(8))) short bf16x8;
typedef __attribute__((ext_vector_type(4))) float f32x4;

__device__ inline unsigned short f2bf(float f) {    // RNE f32 -> bf16 bits
    unsigned u = __float_as_uint(f);
    return (unsigned short)((u + 0x7FFFu + ((u >> 16) & 1u)) >> 16);
}
__device__ inline float bflo(unsigned v) { return __uint_as_float(v << 16); }
__device__ inline float bfhi(unsigned v) { return __uint_as_float(v & 0xFFFF0000u); }

// ---------------------------------------------------------------------------
// kNN + fused layer 1. One wave per query row. (R7/R9-proven, unchanged.)
// ---------------------------------------------------------------------------
__global__ __launch_bounds__(512) void knn_kernel(
    const float* __restrict__ pc, int* __restrict__ nbr,
    const float* __restrict__ W1r, const float* __restrict__ b1,
    const float* __restrict__ W1s, unsigned short* __restrict__ x1)
{
    __shared__ __align__(16) float4 pts[NPTS];        // x,y,z,|p|^2  (32 KB)
    __shared__ unsigned ckey[RPB][CAP];               // 4 KB
    __shared__ unsigned cidx[RPB][CAP];               // 4 KB

    const int b = blockIdx.x >> 8;                    // 256 blocks per batch
    const int rblk = blockIdx.x & 255;
    const float* p = pc + (size_t)b * NPTS * 3;

    for (int t = threadIdx.x; t < NPTS; t += 512) {
        float x = p[t * 3 + 0], y = p[t * 3 + 1], z = p[t * 3 + 2];
        pts[t] = make_float4(x, y, z, x * x + y * y + z * z);
    }
    __syncthreads();

    const int w = threadIdx.x >> 6;
    const int lane = threadIdx.x & 63;
    const int i = rblk * RPB + w;                     // query row in batch
    const float4 pi = pts[i];
    const float piw16 = pi.w + 16.0f;

    unsigned key[32];
    unsigned km = 0xFFFFFFFFu;
    #pragma unroll
    for (int t = 0; t < 32; ++t) {
        float4 c = pts[t * 64 + lane];
        float dot = fmaf(pi.x, c.x, fmaf(pi.y, c.y, pi.z * c.z));
        float d2 = fmaf(-2.0f, dot, piw16 + c.w);
        key[t] = __float_as_uint(d2);
        km = min(km, key[t]);
    }

    unsigned v = km;
    #pragma unroll
    for (int k = 2; k <= 64; k <<= 1) {
        #pragma unroll
        for (int j = k >> 1; j > 0; j >>= 1) {
            unsigned o = (unsigned)__shfl_xor((int)v, j, 64);
            bool sel = ((lane & k) == 0) == ((lane & j) == 0);
            v = sel ? min(v, o) : max(v, o);
        }
    }
    const unsigned T0 = (unsigned)__shfl((int)v, 15, 64);
    // >=16 candidates have key <= T0, and T0 >= true 16th-smallest
    // => {key <= T0} is a superset of the top-16.

    unsigned base = 0;
    #pragma unroll 1
    for (int t = 0; t < 32; ++t) {
        bool pred = key[t] <= T0;
        unsigned long long mask = __ballot(pred);
        if (mask) {
            unsigned prefix = __builtin_amdgcn_mbcnt_hi(
                (unsigned)(mask >> 32),
                __builtin_amdgcn_mbcnt_lo((unsigned)mask, 0));
            unsigned pos = base + prefix;
            if (pred && pos < CAP) {
                ckey[w][pos] = key[t];
                cidx[w][pos] = (unsigned)(t * 64 + lane);
            }
            base += (unsigned)__popcll(mask);
        }
    }
    __threadfence_block();
    const int m = (int)base;

    int* out = nbr + ((size_t)b * NPTS + i) * KNN;
    float ax = 0.f, ay = 0.f, az = 0.f;               // fused position sum

    if (m <= CAP) {
        unsigned k0 = (lane < m) ? ckey[w][lane] : 0xFFFFFFFFu;
        unsigned k1 = (lane + 64 < m) ? ckey[w][lane + 64] : 0xFFFFFFFFu;
        int r0 = 0, r1 = 0;
        if (m <= 64) {
            #pragma unroll 1
            for (int jj = 0; jj < m; ++jj) {
                unsigned kj = ckey[w][jj];
                r0 += (kj < k0) || (kj == k0 && jj < lane);
            }
        } else {
            #pragma unroll 1
            for (int jj = 0; jj < m; ++jj) {
                unsigned kj = ckey[w][jj];
                r0 += (kj < k0) || (kj == k0 && jj < lane);
                r1 += (kj < k1) || (kj == k1 && jj < lane + 64);
            }
        }
        if (lane < m && r0 < KNN) {
            unsigned j = cidx[w][lane];
            out[r0] = (int)j;
            float4 q = pts[j]; ax += q.x; ay += q.y; az += q.z;
        }
        if (m > 64 && lane + 64 < m && r1 < KNN) {
            unsigned j = cidx[w][lane + 64];
            out[r1] = (int)j;
            float4 q = pts[j]; ax += q.x; ay += q.y; az += q.z;
        }
    } else {
        // exact fallback (never taken w/ random data; correctness only)
        unsigned T = 0;
        #pragma unroll 1
        for (int bit = 31; bit >= 0; --bit) {
            unsigned trial = T | (1u << bit);
            int cnt = 0;
            #pragma unroll
            for (int t = 0; t < 32; ++t) cnt += (key[t] < trial);
            #pragma unroll
            for (int off = 32; off; off >>= 1)
                cnt += __shfl_xor(cnt, off, 64);
            if (cnt < KNN) T = trial;
        }
        unsigned bs = 0;
        #pragma unroll 1
        for (int t = 0; t < 32; ++t) {
            bool p1 = key[t] < T;
            unsigned long long mask = __ballot(p1);
            if (mask) {
                unsigned prefix = __builtin_amdgcn_mbcnt_hi(
                    (unsigned)(mask >> 32),
                    __builtin_amdgcn_mbcnt_lo((unsigned)mask, 0));
                if (p1) {
                    out[bs + prefix] = t * 64 + lane;
                    float4 q = pts[t * 64 + lane];
                    ax += q.x; ay += q.y; az += q.z;
                }
                bs += (unsigned)__popcll(mask);
            }
        }
        #pragma unroll 1
        for (int t = 0; t < 32 && bs < KNN; ++t) {
            bool p2 = key[t] == T;
            unsigned long long mask = __ballot(p2);
            if (mask) {
                unsigned prefix = __builtin_amdgcn_mbcnt_hi(
                    (unsigned)(mask >> 32),
                    __builtin_amdgcn_mbcnt_lo((unsigned)mask, 0));
                unsigned pos = bs + prefix;
                if (p2 && pos < KNN) {
                    out[pos] = t * 64 + lane;
                    float4 q = pts[t * 64 + lane];
                    ax += q.x; ay += q.y; az += q.z;
                }
                bs += (unsigned)__popcll(mask);
            }
        }
    }

    #pragma unroll
    for (int off = 32; off; off >>= 1) {
        ax += __shfl_xor(ax, off, 64);
        ay += __shfl_xor(ay, off, 64);
        az += __shfl_xor(az, off, 64);
    }

    unsigned short* xrow = x1 + ((size_t)b * NPTS + i) * HID;
    #pragma unroll
    for (int hh = 0; hh < 2; ++hh) {
        int h = lane + hh * 64;
        float acc = b1[h];
        acc += W1r[h * 3 + 0] * ax + W1r[h * 3 + 1] * ay + W1r[h * 3 + 2] * az;
        acc += W1s[h * 3 + 0] * pi.x + W1s[h * 3 + 1] * pi.y + W1s[h * 3 + 2] * pi.z;
        xrow[h] = f2bf(fmaxf(acc, 0.f));
    }
}

// ---------------------------------------------------------------------------
// Weight conversion: 4 x [128x128] f32 -> bf16.
// ---------------------------------------------------------------------------
__global__ __launch_bounds__(256) void wcvt_kernel(
    const float* __restrict__ a, const float* __restrict__ b,
    const float* __restrict__ c, const float* __restrict__ d,
    unsigned short* __restrict__ out)
{
    int g = blockIdx.x * 256 + threadIdx.x;       // < 65536
    int m = g >> 14;
    const float* s = (m == 0) ? a : (m == 1) ? b : (m == 2) ? c : d;
    out[g] = f2bf(s[g & 16383]);
}

// ---------------------------------------------------------------------------
// Fused gather + GraphConv via bf16 MFMA, v4: latency-hiding restructure.
// R10's 64-pt tile gave grid=512 = 2 blocks/CU TOTAL -> no block pipelining;
// gather latency (L3/HBM, ~600cyc) fully exposed -> ~55 us/conv.
// v4: 16-pt x 128-h tile, 256 thr, grid 2048 = 8 blocks/CU with ~9.6 KB LDS
// (many co-resident + churn). XCD-aware swizzle: batch = blockIdx & 15 ->
// all blocks of a batch on XCD (b&7) [round-robin heuristic]; per-XCD gather
// working set = 2 batches x 512 KB = 1 MB -> L2-resident re-reads.
// Gather: 1 task/thread (pt,c8), 16 loads in 2 explicit 8-deep batches.
// MFMA: 4 waves x (16 pt x 32 h). Coalesced LDS-staged epilogue (R10-proven).
// ---------------------------------------------------------------------------
template <bool RELU, bool OUT_BF16>
__global__ __launch_bounds__(256) void conv_fused(
    const unsigned short* __restrict__ x, const int* __restrict__ nbr,
    const unsigned short* __restrict__ Wr, const unsigned short* __restrict__ Ws,
    const float* __restrict__ bias, void* __restrict__ outv)
{
    // union: bf16 agg tile [16][136] (4.4 KB) / f32 out tile [16][132] (8.4 KB)
    __shared__ __align__(16) char smem[16 * 132 * 4];
    __shared__ int nbrs[16][17];                             // 1.1 KB
    unsigned short (*aggs)[136] = (unsigned short (*)[136])smem;
    float (*outs)[132] = (float (*)[132])smem;

    const int bt = blockIdx.x & 15;                          // batch (XCD swizzle)
    const int p0 = bt * NPTS + (blockIdx.x >> 4) * 16;       // global point base
    const unsigned short* xb = x + ((size_t)bt << 11) * HID; // batch-local rows

    // ---- stage nbr into LDS (1 int/thread) --------------------------------
    nbrs[threadIdx.x >> 4][threadIdx.x & 15] =
        nbr[(size_t)p0 * KNN + threadIdx.x];
    __syncthreads();

    // ---- gather-sum -> bf16 agg tile: task (pt, c8), 2 x 8-deep loads -----
    {
        const int c8 = threadIdx.x & 15, pt = threadIdx.x >> 4;
        const unsigned short* base = xb + c8 * 8;
        float s[8] = {0, 0, 0, 0, 0, 0, 0, 0};
        #pragma unroll
        for (int half = 0; half < 2; ++half) {
            uint4 v[8];
            #pragma unroll
            for (int t = 0; t < 8; ++t) {
                int j = nbrs[pt][half * 8 + t];
                v[t] = *(const uint4*)(base + (size_t)j * HID);
            }
            #pragma unroll
            for (int t = 0; t < 8; ++t) {
                s[0] += bflo(v[t].x); s[1] += bfhi(v[t].x);
                s[2] += bflo(v[t].y); s[3] += bfhi(v[t].y);
                s[4] += bflo(v[t].z); s[5] += bfhi(v[t].z);
                s[6] += bflo(v[t].w); s[7] += bfhi(v[t].w);
            }
        }
        uint4 ov;
        ov.x = (unsigned)f2bf(s[0]) | ((unsigned)f2bf(s[1]) << 16);
        ov.y = (unsigned)f2bf(s[2]) | ((unsigned)f2bf(s[3]) << 16);
        ov.z = (unsigned)f2bf(s[4]) | ((unsigned)f2bf(s[5]) << 16);
        ov.w = (unsigned)f2bf(s[6]) | ((unsigned)f2bf(s[7]) << 16);
        *(uint4*)&aggs[pt][c8 * 8] = ov;
    }
    __syncthreads();

    // ---- MFMA: 4 waves, each 16 pts x 32 h --------------------------------
    const int wv = threadIdx.x >> 6;              // 0..3
    const int lane = threadIdx.x & 63;
    const int h0w = wv * 32;
    const int row = lane & 15;
    const int quad = lane >> 4;

    f32x4 acc[2];
    acc[0] = (f32x4){0, 0, 0, 0};
    acc[1] = (f32x4){0, 0, 0, 0};

    // agg @ Wr^T
    #pragma unroll
    for (int kc = 0; kc < 4; ++kc) {
        bf16x8 a0 = *(const bf16x8*)&aggs[row][quad * 8 + kc * 32];
        #pragma unroll
        for (int n = 0; n < 2; ++n) {
            bf16x8 bb = *(const bf16x8*)&Wr[(size_t)(h0w + n * 16 + row) * HID
                                            + quad * 8 + kc * 32];
            acc[n] = __builtin_amdgcn_mfma_f32_16x16x32_bf16(a0, bb, acc[n], 0, 0, 0);
        }
    }
    // x @ Ws^T
    const unsigned short* xr0 = x + (size_t)(p0 + row) * HID + quad * 8;
    #pragma unroll
    for (int kc = 0; kc < 4; ++kc) {
        bf16x8 a0 = *(const bf16x8*)(xr0 + kc * 32);
        #pragma unroll
        for (int n = 0; n < 2; ++n) {
            bf16x8 bb = *(const bf16x8*)&Ws[(size_t)(h0w + n * 16 + row) * HID
                                            + quad * 8 + kc * 32];
            acc[n] = __builtin_amdgcn_mfma_f32_16x16x32_bf16(a0, bb, acc[n], 0, 0, 0);
        }
    }

    // ---- epilogue: bias/relu -> LDS tile -> coalesced stores --------------
    __syncthreads();                              // all agg reads complete
    #pragma unroll
    for (int n = 0; n < 2; ++n) {
        float bh = bias[h0w + n * 16 + row];
        #pragma unroll
        for (int r = 0; r < 4; ++r) {
            int pt = quad * 4 + r;                // 0..15 in tile
            int hh = h0w + n * 16 + row;          // 0..127
            float vv = acc[n][r] + bh;
            if (RELU) vv = fmaxf(vv, 0.f);
            if (OUT_BF16) aggs[pt][hh] = f2bf(vv);
            else          outs[pt][hh] = vv;
        }
    }
    __syncthreads();

    if (OUT_BF16) {
        unsigned short* o = (unsigned short*)outv;
        int rr = threadIdx.x >> 4, ch = threadIdx.x & 15;   // 256 tasks
        *(uint4*)(o + (size_t)(p0 + rr) * HID + ch * 8) =
            *(const uint4*)&aggs[rr][ch * 8];
    } else {
        float* o = (float*)outv;
        #pragma unroll
        for (int q = 0; q < 2; ++q) {
            int task = q * 256 + threadIdx.x;     // 512 tasks = 16 rows x 32
            int rr = task >> 5, ch = task & 31;
            *(float4*)(o + (size_t)(p0 + rr) * HID + ch * 4) =
                *(const float4*)&outs[rr][ch * 4];
        }
    }
}

// ---------------------------------------------------------------------------
extern "C" void kernel_launch(void* const* d_in, const int* in_sizes, int n_in,
                              void* d_out, int out_size, void* d_ws, size_t ws_size,
                              hipStream_t stream)
{
    const float* pc  = (const float*)d_in[0];
    const float* W1r = (const float*)d_in[1];
    const float* b1  = (const float*)d_in[2];
    const float* W1s = (const float*)d_in[3];
    const float* W2r = (const float*)d_in[4];
    const float* b2  = (const float*)d_in[5];
    const float* W2s = (const float*)d_in[6];
    const float* W3r = (const float*)d_in[7];
    const float* b3  = (const float*)d_in[8];
    const float* W3s = (const float*)d_in[9];
    float* out = (float*)d_out;

    char* ws = (char*)d_ws;
    const size_t MB = 1024 * 1024;
    int*            nbr = (int*)ws;                             // 2 MB
    unsigned short* x1  = (unsigned short*)(ws + 2 * MB);       // 8.39 MB
    unsigned short* x2  = (unsigned short*)(ws + 2 * MB + 8388608);
    unsigned short* wbf = (unsigned short*)(ws + 2 * MB + 2 * 8388608);
    unsigned short* w2r = wbf;
    unsigned short* w2s = wbf + 16384;
    unsigned short* w3r = wbf + 32768;
    unsigned short* w3s = wbf + 49152;

    const int NPOINTS = BATCH * NPTS;                           // 32768

    wcvt_kernel<<<256, 256, 0, stream>>>(W2r, W2s, W3r, W3s, wbf);
    knn_kernel<<<NPOINTS / RPB, 512, 0, stream>>>(pc, nbr, W1r, b1, W1s, x1);

    conv_fused<true, true><<<NPOINTS / 16, 256, 0, stream>>>(
        x1, nbr, w2r, w2s, b2, x2);
    conv_fused<false, false><<<NPOINTS / 16, 256, 0, stream>>>(
        x2, nbr, w3r, w3s, b3, out);
}

// Round 12
// 168.493 us; speedup vs baseline: 1.0804x; 1.0804x over previous
//
#include <hip/hip_runtime.h>
#include <math.h>

#define NPTS 2048
#define BATCH 16
#define KNN 16
#define HID 128
#define NPOINTS (BATCH * NPTS)   // 32768
#define RPB 8          // rows (queries) per block = waves per block
#define CAP 128        // compacted-candidate capacity per wave

typedef __attribute__((ext_vector_type(8))) short bf16x8;
typedef __attribute__((ext_vector_type(4))) float f32x4;

__device__ inline unsigned short f2bf(float f) {    // RNE f32 -> bf16 bits
    unsigned u = __float_as_uint(f);
    return (unsigned short)((u + 0x7FFFu + ((u >> 16) & 1u)) >> 16);
}
__device__ inline float bflo(unsigned v) { return __uint_as_float(v << 16); }
__device__ inline float bfhi(unsigned v) { return __uint_as_float(v & 0xFFFF0000u); }

// Chunk-transposed bf16 layout: T[cc][point][8ch], cc = channel/8 (16 planes).
// Serves: contiguous 32KB/batch staging for the LDS gather, 256B-coalesced
// MFMA A-fragments (8 consecutive k == one chunk), coalesced epilogues.

// ---------------------------------------------------------------------------
// kNN + fused layer 1. One wave per query row. R9-proven structure; tail now
// writes x1 in chunked-T layout via a small LDS stage.
// ---------------------------------------------------------------------------
__global__ __launch_bounds__(512) void knn_kernel(
    const float* __restrict__ pc, int* __restrict__ nbr,
    const float* __restrict__ W1r, const float* __restrict__ b1,
    const float* __restrict__ W1s, unsigned short* __restrict__ x1T)
{
    __shared__ __align__(16) float4 pts[NPTS];        // 32 KB
    __shared__ unsigned ckey[RPB][CAP];               // 4 KB
    __shared__ unsigned cidx[RPB][CAP];               // 4 KB
    __shared__ __align__(16) unsigned short xst[RPB][HID];  // 2 KB

    const int b = blockIdx.x >> 8;                    // 256 blocks per batch
    const int rblk = blockIdx.x & 255;
    const float* p = pc + (size_t)b * NPTS * 3;

    for (int t = threadIdx.x; t < NPTS; t += 512) {
        float x = p[t * 3 + 0], y = p[t * 3 + 1], z = p[t * 3 + 2];
        pts[t] = make_float4(x, y, z, x * x + y * y + z * z);
    }
    __syncthreads();

    const int w = threadIdx.x >> 6;
    const int lane = threadIdx.x & 63;
    const int i = rblk * RPB + w;                     // query row in batch
    const float4 pi = pts[i];
    const float piw16 = pi.w + 16.0f;

    unsigned key[32];
    unsigned km = 0xFFFFFFFFu;
    #pragma unroll
    for (int t = 0; t < 32; ++t) {
        float4 c = pts[t * 64 + lane];
        float dot = fmaf(pi.x, c.x, fmaf(pi.y, c.y, pi.z * c.z));
        float d2 = fmaf(-2.0f, dot, piw16 + c.w);
        key[t] = __float_as_uint(d2);
        km = min(km, key[t]);
    }

    unsigned v = km;
    #pragma unroll
    for (int k = 2; k <= 64; k <<= 1) {
        #pragma unroll
        for (int j = k >> 1; j > 0; j >>= 1) {
            unsigned o = (unsigned)__shfl_xor((int)v, j, 64);
            bool sel = ((lane & k) == 0) == ((lane & j) == 0);
            v = sel ? min(v, o) : max(v, o);
        }
    }
    const unsigned T0 = (unsigned)__shfl((int)v, 15, 64);
    // >=16 candidates <= T0 and T0 >= true 16th => superset of the top-16.

    unsigned base = 0;
    #pragma unroll 1
    for (int t = 0; t < 32; ++t) {
        bool pred = key[t] <= T0;
        unsigned long long mask = __ballot(pred);
        if (mask) {
            unsigned prefix = __builtin_amdgcn_mbcnt_hi(
                (unsigned)(mask >> 32),
                __builtin_amdgcn_mbcnt_lo((unsigned)mask, 0));
            unsigned pos = base + prefix;
            if (pred && pos < CAP) {
                ckey[w][pos] = key[t];
                cidx[w][pos] = (unsigned)(t * 64 + lane);
            }
            base += (unsigned)__popcll(mask);
        }
    }
    __threadfence_block();
    const int m = (int)base;

    int* out = nbr + ((size_t)b * NPTS + i) * KNN;
    float ax = 0.f, ay = 0.f, az = 0.f;               // fused position sum

    if (m <= CAP) {
        unsigned k0 = (lane < m) ? ckey[w][lane] : 0xFFFFFFFFu;
        unsigned k1 = (lane + 64 < m) ? ckey[w][lane + 64] : 0xFFFFFFFFu;
        int r0 = 0, r1 = 0;
        if (m <= 64) {
            #pragma unroll 1
            for (int jj = 0; jj < m; ++jj) {
                unsigned kj = ckey[w][jj];
                r0 += (kj < k0) || (kj == k0 && jj < lane);
            }
        } else {
            #pragma unroll 1
            for (int jj = 0; jj < m; ++jj) {
                unsigned kj = ckey[w][jj];
                r0 += (kj < k0) || (kj == k0 && jj < lane);
                r1 += (kj < k1) || (kj == k1 && jj < lane + 64);
            }
        }
        if (lane < m && r0 < KNN) {
            unsigned j = cidx[w][lane];
            out[r0] = (int)j;
            float4 q = pts[j]; ax += q.x; ay += q.y; az += q.z;
        }
        if (m > 64 && lane + 64 < m && r1 < KNN) {
            unsigned j = cidx[w][lane + 64];
            out[r1] = (int)j;
            float4 q = pts[j]; ax += q.x; ay += q.y; az += q.z;
        }
    } else {
        // exact fallback (never taken w/ random data; correctness only)
        unsigned T = 0;
        #pragma unroll 1
        for (int bit = 31; bit >= 0; --bit) {
            unsigned trial = T | (1u << bit);
            int cnt = 0;
            #pragma unroll
            for (int t = 0; t < 32; ++t) cnt += (key[t] < trial);
            #pragma unroll
            for (int off = 32; off; off >>= 1)
                cnt += __shfl_xor(cnt, off, 64);
            if (cnt < KNN) T = trial;
        }
        unsigned bs = 0;
        #pragma unroll 1
        for (int t = 0; t < 32; ++t) {
            bool p1 = key[t] < T;
            unsigned long long mask = __ballot(p1);
            if (mask) {
                unsigned prefix = __builtin_amdgcn_mbcnt_hi(
                    (unsigned)(mask >> 32),
                    __builtin_amdgcn_mbcnt_lo((unsigned)mask, 0));
                if (p1) {
                    out[bs + prefix] = t * 64 + lane;
                    float4 q = pts[t * 64 + lane];
                    ax += q.x; ay += q.y; az += q.z;
                }
                bs += (unsigned)__popcll(mask);
            }
        }
        #pragma unroll 1
        for (int t = 0; t < 32 && bs < KNN; ++t) {
            bool p2 = key[t] == T;
            unsigned long long mask = __ballot(p2);
            if (mask) {
                unsigned prefix = __builtin_amdgcn_mbcnt_hi(
                    (unsigned)(mask >> 32),
                    __builtin_amdgcn_mbcnt_lo((unsigned)mask, 0));
                unsigned pos = bs + prefix;
                if (p2 && pos < KNN) {
                    out[pos] = t * 64 + lane;
                    float4 q = pts[t * 64 + lane];
                    ax += q.x; ay += q.y; az += q.z;
                }
                bs += (unsigned)__popcll(mask);
            }
        }
    }

    #pragma unroll
    for (int off = 32; off; off >>= 1) {
        ax += __shfl_xor(ax, off, 64);
        ay += __shfl_xor(ay, off, 64);
        az += __shfl_xor(az, off, 64);
    }

    // ---- fused layer 1 -> LDS stage -> chunked-T write --------------------
    #pragma unroll
    for (int hh = 0; hh < 2; ++hh) {
        int h = lane + hh * 64;
        float acc = b1[h];
        acc += W1r[h * 3 + 0] * ax + W1r[h * 3 + 1] * ay + W1r[h * 3 + 2] * az;
        acc += W1s[h * 3 + 0] * pi.x + W1s[h * 3 + 1] * pi.y + W1s[h * 3 + 2] * pi.z;
        xst[w][h] = f2bf(fmaxf(acc, 0.f));
    }
    __syncthreads();
    if (threadIdx.x < RPB * 16) {                 // 128 tasks x 16 B
        int pt = threadIdx.x & 7, cc = threadIdx.x >> 3;
        uint4 vv = *(const uint4*)&xst[pt][cc * 8];
        *(uint4*)&x1T[((size_t)cc * NPOINTS + (size_t)b * NPTS + rblk * RPB + pt) * 8] = vv;
    }
}

// ---------------------------------------------------------------------------
// Weight conversion: 4 x [128x128] f32 -> bf16 chunked-T (wT[cc][h][8]).
// ---------------------------------------------------------------------------
__global__ __launch_bounds__(256) void wcvt_kernel(
    const float* __restrict__ a, const float* __restrict__ b,
    const float* __restrict__ c, const float* __restrict__ d,
    unsigned short* __restrict__ out)
{
    int g = blockIdx.x * 256 + threadIdx.x;       // < 65536
    int m = g >> 14;
    int e = g & 16383;
    int r = e >> 7, cch = e & 127;
    const float* s = (m == 0) ? a : (m == 1) ? b : (m == 2) ? c : d;
    out[m * 16384 + ((cch >> 3) * 128 + r) * 8 + (cch & 7)] = f2bf(s[e]);
}

// ---------------------------------------------------------------------------
// Gather via LDS: block = (batch, chunk). Stages the whole batch's 8-channel
// slice (2048 x 16 B, contiguous read) into LDS at 24 B stride, then each
// thread gathers 16 neighbor slices from LDS (b64 pairs) and writes the agg
// slice chunked-T. Cuts per-conv global gather traffic 134 MB -> ~10 MB.
// Grid index bi: batch = bi & 15 (XCD = bi % 8 heuristic -> nbr L2 locality).
// ---------------------------------------------------------------------------
__global__ __launch_bounds__(1024) void gather_kernel(
    const unsigned short* __restrict__ xT, const int* __restrict__ nbr,
    unsigned short* __restrict__ aggT)
{
    __shared__ __align__(16) unsigned short rows[NPTS * 12];   // 48 KB, 24B/row
    const int b = blockIdx.x & 15;
    const int cc = blockIdx.x >> 4;
    const unsigned short* src = xT + ((size_t)cc * NPOINTS + (size_t)b * NPTS) * 8;

    #pragma unroll
    for (int rr = 0; rr < 2; ++rr) {
        int t = rr * 1024 + threadIdx.x;
        uint4 vv = *(const uint4*)(src + t * 8);
        *(uint2*)&rows[t * 12] = make_uint2(vv.x, vv.y);
        *(uint2*)&rows[t * 12 + 4] = make_uint2(vv.z, vv.w);
    }
    __syncthreads();

    const int* nb = nbr + (size_t)b * NPTS * KNN;
    unsigned short* dst = aggT + ((size_t)cc * NPOINTS + (size_t)b * NPTS) * 8;

    #pragma unroll
    for (int rr = 0; rr < 2; ++rr) {
        int pt = rr * 1024 + threadIdx.x;
        const int4* nr4 = (const int4*)(nb + (size_t)pt * KNN);
        int4 n0 = nr4[0], n1 = nr4[1], n2 = nr4[2], n3 = nr4[3];
        int idx[16] = {n0.x, n0.y, n0.z, n0.w, n1.x, n1.y, n1.z, n1.w,
                       n2.x, n2.y, n2.z, n2.w, n3.x, n3.y, n3.z, n3.w};
        float s[8] = {0, 0, 0, 0, 0, 0, 0, 0};
        #pragma unroll
        for (int t = 0; t < KNN; ++t) {
            int j = idx[t];
            uint2 va = *(const uint2*)&rows[j * 12];
            uint2 vb = *(const uint2*)&rows[j * 12 + 4];
            s[0] += bflo(va.x); s[1] += bfhi(va.x);
            s[2] += bflo(va.y); s[3] += bfhi(va.y);
            s[4] += bflo(vb.x); s[5] += bfhi(vb.x);
            s[6] += bflo(vb.y); s[7] += bfhi(vb.y);
        }
        uint4 ov;
        ov.x = (unsigned)f2bf(s[0]) | ((unsigned)f2bf(s[1]) << 16);
        ov.y = (unsigned)f2bf(s[2]) | ((unsigned)f2bf(s[3]) << 16);
        ov.z = (unsigned)f2bf(s[4]) | ((unsigned)f2bf(s[5]) << 16);
        ov.w = (unsigned)f2bf(s[6]) | ((unsigned)f2bf(s[7]) << 16);
        *(uint4*)(dst + (size_t)pt * 8) = ov;
    }
}

// ---------------------------------------------------------------------------
// Pure GEMM conv: out[p][h] = Wr@agg_p + Ws@x_p + b (+relu). All operands
// chunked-T -> every read 256 B coalesced; zero random access.
// 512 thr, 64 pt x 128 h, wave tile 32x32 (2x2 MFMA). LDS-staged epilogue:
// conv1 -> x2 chunked-T bf16; conv2 -> row-major f32 out.
// D layout [verified R5+]: point = quad*4+reg, h = lane&15.
// ---------------------------------------------------------------------------
template <bool RELU, bool OUT_CHUNKED>
__global__ __launch_bounds__(512) void convmm_kernel(
    const unsigned short* __restrict__ aggT, const unsigned short* __restrict__ xT,
    const unsigned short* __restrict__ wTr, const unsigned short* __restrict__ wTs,
    const float* __restrict__ bias, void* __restrict__ outv)
{
    // union: bf16 tile [64][136] (17.4 KB) / f32 tile [64][132] (33.8 KB)
    __shared__ __align__(16) char smem[64 * 132 * 4];
    unsigned short (*obf)[136] = (unsigned short (*)[136])smem;
    float (*of32)[132] = (float (*)[132])smem;

    const int p0 = blockIdx.x * 64;
    const int wv = threadIdx.x >> 6;
    const int lane = threadIdx.x & 63;
    const int ptw = (wv & 1) * 32;                // 0 / 32
    const int h0w = (wv >> 1) * 32;               // 0 / 32 / 64 / 96
    const int row = lane & 15;
    const int quad = lane >> 4;

    f32x4 acc[2][2];
    #pragma unroll
    for (int i = 0; i < 2; ++i)
        #pragma unroll
        for (int n = 0; n < 2; ++n) acc[i][n] = (f32x4){0, 0, 0, 0};

    // agg @ Wr^T
    #pragma unroll
    for (int kc = 0; kc < 4; ++kc) {
        const int pl = quad + 4 * kc;             // chunk plane = k/8
        bf16x8 a0 = *(const bf16x8*)(aggT + ((size_t)pl * NPOINTS + p0 + ptw + row) * 8);
        bf16x8 a1 = *(const bf16x8*)(aggT + ((size_t)pl * NPOINTS + p0 + ptw + 16 + row) * 8);
        #pragma unroll
        for (int n = 0; n < 2; ++n) {
            bf16x8 bb = *(const bf16x8*)(wTr + ((size_t)pl * HID + h0w + n * 16 + row) * 8);
            acc[0][n] = __builtin_amdgcn_mfma_f32_16x16x32_bf16(a0, bb, acc[0][n], 0, 0, 0);
            acc[1][n] = __builtin_amdgcn_mfma_f32_16x16x32_bf16(a1, bb, acc[1][n], 0, 0, 0);
        }
    }
    // x @ Ws^T
    #pragma unroll
    for (int kc = 0; kc < 4; ++kc) {
        const int pl = quad + 4 * kc;
        bf16x8 a0 = *(const bf16x8*)(xT + ((size_t)pl * NPOINTS + p0 + ptw + row) * 8);
        bf16x8 a1 = *(const bf16x8*)(xT + ((size_t)pl * NPOINTS + p0 + ptw + 16 + row) * 8);
        #pragma unroll
        for (int n = 0; n < 2; ++n) {
            bf16x8 bb = *(const bf16x8*)(wTs + ((size_t)pl * HID + h0w + n * 16 + row) * 8);
            acc[0][n] = __builtin_amdgcn_mfma_f32_16x16x32_bf16(a0, bb, acc[0][n], 0, 0, 0);
            acc[1][n] = __builtin_amdgcn_mfma_f32_16x16x32_bf16(a1, bb, acc[1][n], 0, 0, 0);
        }
    }

    // ---- epilogue: bias/relu -> LDS tile -> coalesced stores --------------
    #pragma unroll
    for (int n = 0; n < 2; ++n) {
        float bh = bias[h0w + n * 16 + row];
        #pragma unroll
        for (int i = 0; i < 2; ++i) {
            #pragma unroll
            for (int r = 0; r < 4; ++r) {
                int pt = ptw + i * 16 + quad * 4 + r;     // 0..63 in tile
                int hh = h0w + n * 16 + row;              // 0..127
                float vv = acc[i][n][r] + bh;
                if (RELU) vv = fmaxf(vv, 0.f);
                if (OUT_CHUNKED) obf[pt][hh] = f2bf(vv);
                else             of32[pt][hh] = vv;
            }
        }
    }
    __syncthreads();

    if (OUT_CHUNKED) {
        unsigned short* o = (unsigned short*)outv;        // chunked-T bf16
        #pragma unroll
        for (int q = 0; q < 2; ++q) {
            int task = q * 512 + threadIdx.x;     // 1024 = 64 pts x 16 cc
            int pt = task & 63, cc = task >> 6;
            *(uint4*)(o + ((size_t)cc * NPOINTS + p0 + pt) * 8) =
                *(const uint4*)&obf[pt][cc * 8];
        }
    } else {
        float* o = (float*)outv;                          // row-major f32
        #pragma unroll
        for (int q = 0; q < 4; ++q) {
            int task = q * 512 + threadIdx.x;     // 2048 = 64 rows x 32 chunks
            int rr = task >> 5, ch = task & 31;
            *(float4*)(o + (size_t)(p0 + rr) * HID + ch * 4) =
                *(const float4*)&of32[rr][ch * 4];
        }
    }
}

// ---------------------------------------------------------------------------
extern "C" void kernel_launch(void* const* d_in, const int* in_sizes, int n_in,
                              void* d_out, int out_size, void* d_ws, size_t ws_size,
                              hipStream_t stream)
{
    const float* pc  = (const float*)d_in[0];
    const float* W1r = (const float*)d_in[1];
    const float* b1  = (const float*)d_in[2];
    const float* W1s = (const float*)d_in[3];
    const float* W2r = (const float*)d_in[4];
    const float* b2  = (const float*)d_in[5];
    const float* W2s = (const float*)d_in[6];
    const float* W3r = (const float*)d_in[7];
    const float* b3  = (const float*)d_in[8];
    const float* W3s = (const float*)d_in[9];
    float* out = (float*)d_out;

    char* ws = (char*)d_ws;
    const size_t MB = 1024 * 1024;
    const size_t XSZ = (size_t)NPOINTS * HID * 2;                // 8.39 MB
    int*            nbr  = (int*)ws;                             // 2 MB
    unsigned short* x1T  = (unsigned short*)(ws + 2 * MB);
    unsigned short* x2T  = (unsigned short*)(ws + 2 * MB + XSZ);
    unsigned short* aggT = (unsigned short*)(ws + 2 * MB + 2 * XSZ);
    unsigned short* wT   = (unsigned short*)(ws + 2 * MB + 3 * XSZ);
    unsigned short* w2rT = wT;
    unsigned short* w2sT = wT + 16384;
    unsigned short* w3rT = wT + 32768;
    unsigned short* w3sT = wT + 49152;

    wcvt_kernel<<<256, 256, 0, stream>>>(W2r, W2s, W3r, W3s, wT);
    knn_kernel<<<NPOINTS / RPB, 512, 0, stream>>>(pc, nbr, W1r, b1, W1s, x1T);

    gather_kernel<<<256, 1024, 0, stream>>>(x1T, nbr, aggT);
    convmm_kernel<true, true><<<NPOINTS / 64, 512, 0, stream>>>(
        aggT, x1T, w2rT, w2sT, b2, x2T);

    gather_kernel<<<256, 1024, 0, stream>>>(x2T, nbr, aggT);
    convmm_kernel<false, false><<<NPOINTS / 64, 512, 0, stream>>>(
        aggT, x2T, w3rT, w3sT, b3, out);
}